// Round 10
// baseline (2652.973 us; speedup 1.0000x reference)
//
#include <hip/hip_runtime.h>
#include <hip/hip_bf16.h>

#define NPTS 20000
#define NE   320000
#define KNNK 16

typedef __attribute__((ext_vector_type(8))) short bf16x8;
typedef __attribute__((ext_vector_type(4))) float f32x4;

// ---- ws layout (float offsets) ---- total 1,662,240 floats = 6,648,960 B
// x1 region: per-row 256B = [64 bf16 hi | 64 bf16 lo] after k_conv (fp32 before)
#define OFF_X1   0
#define OFF_SQ   (OFF_X1 + NPTS*64)          // 1,280,000
#define OFF_WB   (OFF_SQ + NPTS)             // 1,300,000
#define WB_W1A  0
#define WB_B1A  384
#define WB_W1BT 448
#define WB_B1B  4544
#define WB_W2A  4608      // (128,64)
#define WB_B2A  12800
#define WB_W2B  12864     // (64,64)
#define WB_B2B  16960
#define WB_WE   17024     // (64,256)
#define WB_BE   33408
#define WB_WP   33664
#define WB_BP   37760
#define WB_WR1  37824
#define WB_BR1  41920
#define WB_WR2  41984
#define WB_BR2  42176
#define WB_TOT  42240
#define OFF_NBR  (OFF_WB + WB_TOT)           // int32, 320,000
#define WS_TOT_FLOATS (OFF_NBR + NPTS*KNNK)
#define WS_NEED_BYTES ((size_t)WS_TOT_FLOATS * 4)

__global__ __launch_bounds__(256) void k_out_zero(float* out, int nelem) {
    int i = blockIdx.x * 256 + threadIdx.x;
    if (i < nelem) out[i] = 0.0f;
}

__global__ __launch_bounds__(256) void k_zero(float* p, int nfloat4) {
    int i = blockIdx.x * 256 + threadIdx.x;
    if (i < nfloat4) { float4 z = {0.f,0.f,0.f,0.f}; ((float4*)p)[i] = z; }
}

__global__ __launch_bounds__(256) void k_prep(
    const float* W1a, const float* b1a,
    const float* W1b, const float* b1b,
    const float* W2a, const float* b2a,
    const float* W2b, const float* b2b,
    const float* We,  const float* be,
    const float* Wp,  const float* bp,
    const float* Wr1, const float* br1,
    const float* Wr2, const float* br2,
    float* wb)
{
    int t = blockIdx.x * blockDim.x + threadIdx.x;
    int gs = gridDim.x * blockDim.x;
    for (int i = t; i < 384;  i += gs) wb[WB_W1A+i] = W1a[i];
    for (int i = t; i < 64;   i += gs) wb[WB_B1A+i] = b1a[i];
    for (int i = t; i < 4096; i += gs) { int j=i>>6, k=i&63; wb[WB_W1BT+i] = W1b[k*64+j]; }
    for (int i = t; i < 64;   i += gs) wb[WB_B1B+i] = b1b[i];
    for (int i = t; i < 8192; i += gs) wb[WB_W2A+i] = W2a[i];
    for (int i = t; i < 64;   i += gs) wb[WB_B2A+i] = b2a[i];
    for (int i = t; i < 4096; i += gs) wb[WB_W2B+i] = W2b[i];
    for (int i = t; i < 64;   i += gs) wb[WB_B2B+i] = b2b[i];
    for (int i = t; i < 16384;i += gs) wb[WB_WE+i]  = We[i];
    for (int i = t; i < 256;  i += gs) wb[WB_BE+i]  = be[i];
    for (int i = t; i < 4096; i += gs) wb[WB_WP+i]  = Wp[i];
    for (int i = t; i < 64;   i += gs) wb[WB_BP+i]  = bp[i];
    for (int i = t; i < 4096; i += gs) wb[WB_WR1+i] = Wr1[i];
    for (int i = t; i < 64;   i += gs) wb[WB_BR1+i] = br1[i];
    for (int i = t; i < 192;  i += gs) wb[WB_WR2+i] = Wr2[i];
    for (int i = t; i < 3;    i += gs) wb[WB_BR2+i] = br2[i];
}

// Stage 1: per-edge MLP (6->64->64, relu both) + atomic segment-max into x1 (fp32).
// Read-before-atomic: x1u monotone non-decreasing -> stale read >= a is safe to skip.
__global__ __launch_bounds__(256) void k_edge_mlp(
    const float* __restrict__ dep, const int* __restrict__ ei,
    const float* __restrict__ wb, unsigned int* __restrict__ x1u)
{
    int e = blockIdx.x * 256 + threadIdx.x;
    if (e >= NE) return;
    int s = ei[e];
    int d = ei[NE + e];
    s = s < 0 ? 0 : (s >= NPTS ? NPTS-1 : s);
    d = d < 0 ? 0 : (d >= NPTS ? NPTS-1 : d);
    float xi0 = dep[d*3+0];
    float xi1 = dep[d*3+1];
    float xi2 = dep[d*3+2];
    float xj0 = dep[s*3+0];
    float xj1 = dep[s*3+1];
    float xj2 = dep[s*3+2];
    float in6[6] = { xi0, xi1, xi2, xj0-xi0, xj1-xi1, xj2-xi2 };
    const float* W1a  = wb + WB_W1A;
    const float* b1a  = wb + WB_B1A;
    const float* W1bT = wb + WB_W1BT;
    const float* b1b  = wb + WB_B1B;
    float h1[64];
#pragma unroll
    for (int j = 0; j < 64; ++j) {
        float a = b1a[j];
#pragma unroll
        for (int i = 0; i < 6; ++i) a = fmaf(in6[i], W1a[i*64+j], a);
        h1[j] = fmaxf(a, 0.0f);
    }
    unsigned int* dst = x1u + d*64;
    int woff = (((blockIdx.x << 2) + (threadIdx.x >> 6)) & 3) << 4;  // wave-uniform
    for (int j = 0; j < 64; ++j) {
        int jj = (j + woff) & 63;
        float a = b1b[jj];
        const float* wr = W1bT + jj*64;
#pragma unroll
        for (int i = 0; i < 64; ++i) a = fmaf(h1[i], wr[i], a);
        a = fmaxf(a, 0.0f);
        unsigned int au = __float_as_uint(a);
        if (au > dst[jj]) atomicMax(dst + jj, au);
    }
}

// Convert x1 rows fp32 -> [hi bf16 x64 | lo bf16 x64] IN PLACE, and write sq (from fp32).
__global__ __launch_bounds__(256) void k_conv(float* __restrict__ x1, float* __restrict__ sq) {
    int n = blockIdx.x * 256 + threadIdx.x;
    if (n >= NPTS) return;
    float* base = x1 + n*64;
    float4 r[16];
#pragma unroll
    for (int i = 0; i < 16; ++i) r[i] = ((const float4*)base)[i];
    float s = 0.f;
#pragma unroll
    for (int i = 0; i < 16; ++i) s += r[i].x*r[i].x + r[i].y*r[i].y + r[i].z*r[i].z + r[i].w*r[i].w;
    sq[n] = s;
    unsigned int* hi = (unsigned int*)base;          // bytes [0,128)
    unsigned int* lo = (unsigned int*)(base + 32);   // bytes [128,256)
#pragma unroll
    for (int j = 0; j < 8; ++j) {
        float v[8] = { r[2*j].x, r[2*j].y, r[2*j].z, r[2*j].w,
                       r[2*j+1].x, r[2*j+1].y, r[2*j+1].z, r[2*j+1].w };
        unsigned int hb[8], lb[8];
#pragma unroll
        for (int e = 0; e < 8; ++e) {
            unsigned int u = __float_as_uint(v[e]);
            hb[e] = (u + 0x7fffu + ((u >> 16) & 1u)) >> 16;           // RNE bf16
            float hf = __uint_as_float(hb[e] << 16);
            float lf = v[e] - hf;
            unsigned int ul = __float_as_uint(lf);
            lb[e] = (ul + 0x7fffu + ((ul >> 16) & 1u)) >> 16;
        }
        uint4 hp, lp;
        hp.x = hb[0] | (hb[1] << 16); hp.y = hb[2] | (hb[3] << 16);
        hp.z = hb[4] | (hb[5] << 16); hp.w = hb[6] | (hb[7] << 16);
        lp.x = lb[0] | (lb[1] << 16); lp.y = lb[2] | (lb[3] << 16);
        lp.z = lb[4] | (lb[5] << 16); lp.w = lb[6] | (lb[7] << 16);
        ((uint4*)hi)[j] = hp;
        ((uint4*)lo)[j] = lp;
    }
}

// KNN v5.1 (MFMA split-bf16): 32 queries/block -> 625 blocks, 512 threads,
// c-tile 128, register prefetch of next c-tile overlapping selection.
// FIX vs v5: prefetch row advance is prow[i]+128 (prow already absolute).
#define RP  136   // staging row pitch in shorts (272 B)
#define DTQ 36    // dT pitch in words ([c][q], q=32)
#define QB  32
__global__ __launch_bounds__(512) void k_knn(
    const float* __restrict__ x1, const float* __restrict__ sqv,
    int* __restrict__ nbr)
{
    __shared__ __align__(16) unsigned short qbuf[QB*RP];        // 8704 B
    __shared__ __align__(16) unsigned char  cbuf_raw[128*RP*2]; // 34816 B (c-tiles / dT / dump alias)
    __shared__ float ssq[128];
    unsigned short* cbuf = (unsigned short*)cbuf_raw;           // [128][RP]
    float* dT = (float*)cbuf_raw;                               // [128 c][DTQ q]
    const int t  = threadIdx.x;
    const int n0 = blockIdx.x * QB;

    // stage q tile: 32 rows x 256 B (hi|lo)
    {
        int row = t >> 4, off = t & 15;
        if (row < QB) {
            uint4 v = make_uint4(0,0,0,0);
            if (n0 + row < NPTS) v = ((const uint4*)(x1 + (n0+row)*64))[off];
            *(uint4*)&qbuf[row*RP + off*8] = v;
        }
    }
    __syncthreads();

    const int lane15 = t & 15;
    const int quad   = (t >> 4) & 3;
    const int w   = t >> 6;
    const int qsw = w & 1;        // q strip of 16
    const int cs  = w >> 1;       // c strip of 32
    bf16x8 Ah[2], Al[2];
    {
        const unsigned short* qr = &qbuf[(qsw*16 + lane15)*RP + quad*8];
        Ah[0] = *(const bf16x8*)(qr);
        Ah[1] = *(const bf16x8*)(qr + 32);
        Al[0] = *(const bf16x8*)(qr + 64);
        Al[1] = *(const bf16x8*)(qr + 96);
    }
    const int selq = t & 31, sub = t >> 5;   // t<256 -> sub in [0,8)
    const bool selact = (t < 256);
    float bd[16]; int bi[16];
#pragma unroll
    for (int m = 0; m < 16; ++m) { bd[m] = 1e30f; bi[m] = -1; }
    float wv = 1e30f; int wi = 0;

    // prefetch tile 0 (prow = absolute row staged for the upcoming tile)
    uint4 pv[4];
    int prow[4], poff[4];
#pragma unroll
    for (int i = 0; i < 4; ++i) {
        int ch = i*512 + t;
        prow[i] = ch >> 4; poff[i] = ch & 15;
        pv[i] = make_uint4(0,0,0,0);
        if (prow[i] < NPTS) pv[i] = ((const uint4*)(x1 + prow[i]*64))[poff[i]];
    }
    float sreg = (t < 128 && t < NPTS) ? sqv[t] : 1e30f;

    const int ntile = (NPTS + 127) / 128;
    for (int tile = 0; tile < ntile; ++tile) {
        const int c0 = tile * 128;
        __syncthreads();   // prev selection done reading dT; cbuf free
#pragma unroll
        for (int i = 0; i < 4; ++i)
            *(uint4*)&cbuf[(prow[i] - c0)*RP + poff[i]*8] = pv[i];
        if (t < 128) ssq[t] = sreg;
        __syncthreads();

        f32x4 acc[2];
#pragma unroll
        for (int t4 = 0; t4 < 2; ++t4) acc[t4] = (f32x4){0.f,0.f,0.f,0.f};
#pragma unroll
        for (int t4 = 0; t4 < 2; ++t4) {
            const unsigned short* cr = &cbuf[(cs*32 + t4*16 + lane15)*RP + quad*8];
            bf16x8 Bh0 = *(const bf16x8*)(cr);
            bf16x8 Bh1 = *(const bf16x8*)(cr + 32);
            bf16x8 Bl0 = *(const bf16x8*)(cr + 64);
            bf16x8 Bl1 = *(const bf16x8*)(cr + 96);
            acc[t4] = __builtin_amdgcn_mfma_f32_16x16x32_bf16(Ah[0], Bh0, acc[t4], 0, 0, 0);
            acc[t4] = __builtin_amdgcn_mfma_f32_16x16x32_bf16(Al[0], Bh0, acc[t4], 0, 0, 0);
            acc[t4] = __builtin_amdgcn_mfma_f32_16x16x32_bf16(Ah[0], Bl0, acc[t4], 0, 0, 0);
            acc[t4] = __builtin_amdgcn_mfma_f32_16x16x32_bf16(Ah[1], Bh1, acc[t4], 0, 0, 0);
            acc[t4] = __builtin_amdgcn_mfma_f32_16x16x32_bf16(Al[1], Bh1, acc[t4], 0, 0, 0);
            acc[t4] = __builtin_amdgcn_mfma_f32_16x16x32_bf16(Ah[1], Bl1, acc[t4], 0, 0, 0);
        }
        __syncthreads();   // all cbuf reads done; dT may overwrite
#pragma unroll
        for (int t4 = 0; t4 < 2; ++t4) {
            int c = cs*32 + t4*16 + lane15;
            float4 o; o.x = acc[t4][0]; o.y = acc[t4][1]; o.z = acc[t4][2]; o.w = acc[t4][3];
            *(float4*)&dT[c*DTQ + qsw*16 + quad*4] = o;
        }
        __syncthreads();

        // prefetch next tile (latency overlaps selection below)
        const int c0n = c0 + 128;
        if (c0n < NPTS) {
#pragma unroll
            for (int i = 0; i < 4; ++i) {
                int row = prow[i] + 128;              // FIX: prow is already absolute
                pv[i] = make_uint4(0,0,0,0);
                if (row < NPTS) pv[i] = ((const uint4*)(x1 + row*64))[poff[i]];
                prow[i] = row;
            }
            sreg = (t < 128 && c0n + t < NPTS) ? sqv[c0n + t] : 1e30f;
        }

        if (selact) {
            const float* dcol = dT + selq;
#pragma unroll
            for (int h = 0; h < 2; ++h) {
                int cb8 = sub*16 + h*8;
                float e0 = fmaf(-2.0f, dcol[(cb8+0)*DTQ], ssq[cb8+0]);
                float e1 = fmaf(-2.0f, dcol[(cb8+1)*DTQ], ssq[cb8+1]);
                float e2 = fmaf(-2.0f, dcol[(cb8+2)*DTQ], ssq[cb8+2]);
                float e3 = fmaf(-2.0f, dcol[(cb8+3)*DTQ], ssq[cb8+3]);
                float e4 = fmaf(-2.0f, dcol[(cb8+4)*DTQ], ssq[cb8+4]);
                float e5 = fmaf(-2.0f, dcol[(cb8+5)*DTQ], ssq[cb8+5]);
                float e6 = fmaf(-2.0f, dcol[(cb8+6)*DTQ], ssq[cb8+6]);
                float e7 = fmaf(-2.0f, dcol[(cb8+7)*DTQ], ssq[cb8+7]);
                float mn = fminf(fminf(fminf(e0,e1),fminf(e2,e3)),
                                 fminf(fminf(e4,e5),fminf(e6,e7)));
                if (mn < wv) {
                    float ee[8] = {e0,e1,e2,e3,e4,e5,e6,e7};
#pragma unroll
                    for (int ii = 0; ii < 8; ++ii) {
                        float d2 = ee[ii];
                        int cg = c0 + cb8 + ii;
                        if (d2 < wv && cg < NPTS) {
#pragma unroll
                            for (int m = 0; m < 16; ++m) if (m == wi) { bd[m] = d2; bi[m] = cg; }
                            wv = bd[0]; wi = 0;
#pragma unroll
                            for (int m = 1; m < 16; ++m) if (bd[m] > wv) { wv = bd[m]; wi = m; }
                        }
                    }
                }
            }
        }
    }
    __syncthreads();   // staging regions dead; reuse as dump
    float* fd = (float*)cbuf_raw;                  // [32][129]
    int*   fi = (int*)cbuf_raw + QB*129;           // [32][129]
    if (selact) {
#pragma unroll
        for (int m = 0; m < 16; ++m) {
            fd[selq*129 + sub*16 + m] = bd[m];
            fi[selq*129 + sub*16 + m] = bi[m];
        }
    }
    __syncthreads();
    if (t < QB && n0 + t < NPTS) {
        const float* dls = fd + t*129;
        const int*   ils = fi + t*129;
        float lastd = -1e38f; int lasti = -1;
        for (int r = 0; r < 16; ++r) {
            float best = 1e30f; int bidx = 0;
            for (int m = 0; m < 128; ++m) {
                float dv2 = dls[m]; int iv = ils[m];
                bool gt = (dv2 > lastd) || (dv2 == lastd && iv > lasti);
                bool lt = (dv2 < best)  || (dv2 == best  && iv < bidx);
                if (gt && lt) { best = dv2; bidx = iv; }
            }
            int bc = bidx < 0 ? 0 : (bidx >= NPTS ? NPTS-1 : bidx);
            nbr[(n0 + t)*16 + r] = bc;
            lastd = best; lasti = bidx;
        }
    }
}

__device__ inline float bf2f(unsigned short u) {
    return __uint_as_float(((unsigned int)u) << 16);
}

// Fused stage-2 MLP (128->64->64, relu, max over 16 nbrs) + head. x1 rows are hi|lo bf16.
__global__ __launch_bounds__(64) void k_fuse(
    const float* __restrict__ x1, const int* __restrict__ nbr,
    const float* __restrict__ wb, float* __restrict__ out)
{
    __shared__ __align__(16) float sxr[64];
    __shared__ __align__(16) float svec[64];
    __shared__ __align__(16) float sx2[64];
    __shared__ int snb[16];
    int n = blockIdx.x;
    int t = threadIdx.x;
    {
        const unsigned short* xr = (const unsigned short*)(x1 + n*64);
        sxr[t] = bf2f(xr[t]) + bf2f(xr[64+t]);
    }
    if (t < 16) snb[t] = nbr[n*16 + t];
    __syncthreads();
    const float* W2a = wb + WB_W2A;   // (128,64)
    const float* W2b = wb + WB_W2B;   // (64,64)
    const float4* sx4 = (const float4*)sxr;
    const float4* sv4 = (const float4*)svec;
    float A = wb[WB_B2A + t];
#pragma unroll
    for (int i4 = 0; i4 < 16; ++i4) {
        float4 v = sx4[i4];
        const float* wr = W2a + i4*256 + t;
        A = fmaf(v.x, wr[0], A); A = fmaf(v.y, wr[64], A);
        A = fmaf(v.z, wr[128], A); A = fmaf(v.w, wr[192], A);
    }
    float x2v = 0.0f;                 // z_k >= 0 (post-relu) -> 0-init == max
    for (int k = 0; k < 16; ++k) {
        int nb = snb[k];
        {
            const unsigned short* yr = (const unsigned short*)(x1 + nb*64);
            svec[t] = bf2f(yr[t]) + bf2f(yr[64+t]);
        }
        __syncthreads();
        float h = A;
#pragma unroll
        for (int i4 = 0; i4 < 16; ++i4) {
            float4 v = sv4[i4];
            float4 u = sx4[i4];
            const float* wr = W2a + (64 + i4*4)*64 + t;
            h = fmaf(v.x-u.x, wr[0], h); h = fmaf(v.y-u.y, wr[64], h);
            h = fmaf(v.z-u.z, wr[128], h); h = fmaf(v.w-u.w, wr[192], h);
        }
        h = fmaxf(h, 0.f);
        __syncthreads();
        svec[t] = h;
        __syncthreads();
        float z = wb[WB_B2B + t];
#pragma unroll
        for (int i4 = 0; i4 < 16; ++i4) {
            float4 v = sv4[i4];
            const float* wr = W2b + i4*256 + t;
            z = fmaf(v.x, wr[0], z); z = fmaf(v.y, wr[64], z);
            z = fmaf(v.z, wr[128], z); z = fmaf(v.w, wr[192], z);
        }
        x2v = fmaxf(x2v, fmaxf(z, 0.f));
        __syncthreads();
    }
    sx2[t] = x2v;
    __syncthreads();
    const float4* sx24 = (const float4*)sx2;
    const float* We  = wb + WB_WE;
    const float* Wp  = wb + WB_WP;
    const float* Wr1 = wb + WB_WR1;
    const float* Wr2 = wb + WB_WR2;
    for (int r = 0; r < 4; ++r) {
        float xe = wb[WB_BE + r*64 + t];
#pragma unroll
        for (int i4 = 0; i4 < 16; ++i4) {
            float4 v = sx24[i4];
            const float* wr = We + i4*1024 + r*64 + t;
            xe = fmaf(v.x, wr[0], xe); xe = fmaf(v.y, wr[256], xe);
            xe = fmaf(v.z, wr[512], xe); xe = fmaf(v.w, wr[768], xe);
        }
        svec[t] = xe;
        __syncthreads();
        float ft = wb[WB_BP + t];
#pragma unroll
        for (int i4 = 0; i4 < 16; ++i4) {
            float4 v = sv4[i4];
            const float* wr = Wp + i4*256 + t;
            ft = fmaf(v.x, wr[0], ft); ft = fmaf(v.y, wr[64], ft);
            ft = fmaf(v.z, wr[128], ft); ft = fmaf(v.w, wr[192], ft);
        }
        __syncthreads();
        svec[t] = ft;
        __syncthreads();
        float hh = wb[WB_BR1 + t];
#pragma unroll
        for (int i4 = 0; i4 < 16; ++i4) {
            float4 v = sv4[i4];
            const float* wr = Wr1 + i4*256 + t;
            hh = fmaf(v.x, wr[0], hh); hh = fmaf(v.y, wr[64], hh);
            hh = fmaf(v.z, wr[128], hh); hh = fmaf(v.w, wr[192], hh);
        }
        hh = fmaxf(hh, 0.f);
        __syncthreads();
        svec[t] = hh;
        __syncthreads();
        if (t < 3) {
            float o = wb[WB_BR2 + t];
            for (int i = 0; i < 64; ++i) o = fmaf(svec[i], Wr2[i*3 + t], o);
            int m = r * NPTS + n;
            out[m*3 + t] = o;
        }
        __syncthreads();
    }
}

extern "C" void kernel_launch(void* const* d_in, const int* in_sizes, int n_in,
                              void* d_out, int out_size, void* d_ws, size_t ws_size,
                              hipStream_t stream)
{
    const float* dep = (const float*)d_in[0];
    const float* W1a = (const float*)d_in[1];
    const float* b1a = (const float*)d_in[2];
    const float* W1b = (const float*)d_in[3];
    const float* b1b = (const float*)d_in[4];
    const float* W2a = (const float*)d_in[5];
    const float* b2a = (const float*)d_in[6];
    const float* W2b = (const float*)d_in[7];
    const float* b2b = (const float*)d_in[8];
    const float* We  = (const float*)d_in[9];
    const float* be  = (const float*)d_in[10];
    const float* Wp  = (const float*)d_in[11];
    const float* bp  = (const float*)d_in[12];
    const float* Wr1 = (const float*)d_in[13];
    const float* br1 = (const float*)d_in[14];
    const float* Wr2 = (const float*)d_in[15];
    const float* br2 = (const float*)d_in[16];
    const int* ei = (const int*)d_in[17];

    if (ws_size < WS_NEED_BYTES || d_ws == nullptr) {
        k_out_zero<<<(out_size + 255)/256, 256, 0, stream>>>((float*)d_out, out_size);
        return;
    }

    float* ws   = (float*)d_ws;
    float* x1   = ws + OFF_X1;
    float* sq   = ws + OFF_SQ;
    float* wbuf = ws + OFF_WB;
    int*   nbr  = (int*)(ws + OFF_NBR);

    k_zero<<<(NPTS*64/4 + 255)/256, 256, 0, stream>>>(x1, NPTS*64/4);
    k_prep<<<64, 256, 0, stream>>>(W1a,b1a,W1b,b1b,W2a,b2a,W2b,b2b,We,be,Wp,bp,Wr1,br1,Wr2,br2, wbuf);
    k_edge_mlp<<<NE/256, 256, 0, stream>>>(dep, ei, wbuf, (unsigned int*)x1);
    k_conv<<<(NPTS+255)/256, 256, 0, stream>>>(x1, sq);
    k_knn<<<NPTS/QB, 512, 0, stream>>>(x1, sq, nbr);
    k_fuse<<<NPTS, 64, 0, stream>>>(x1, nbr, wbuf, (float*)d_out);
}

// Round 11
// 2181.848 us; speedup vs baseline: 1.2159x; 1.2159x over previous
//
#include <hip/hip_runtime.h>
#include <hip/hip_bf16.h>

#define NPTS 20000
#define NE   320000
#define KNNK 16

typedef __attribute__((ext_vector_type(8))) short bf16x8;
typedef __attribute__((ext_vector_type(4))) float f32x4;

// ---- ws layout (float offsets) ----
// x1 region: per-row 256B = [64 bf16 hi | 64 bf16 lo] after k_conv (fp32 before)
#define OFF_X1   0
#define OFF_SQ   (OFF_X1 + NPTS*64)          // 1,280,000 (CSR counts/cursor alias pre-conv)
#define OFF_WB   (OFF_SQ + NPTS)             // 1,300,000
#define WB_W1A  0
#define WB_B1A  384
#define WB_W1BT 448
#define WB_B1B  4544
#define WB_W2A  4608      // (128,64)
#define WB_B2A  12800
#define WB_W2B  12864     // (64,64)
#define WB_B2B  16960
#define WB_WE   17024     // (64,256)
#define WB_BE   33408
#define WB_WP   33664
#define WB_BP   37760
#define WB_WR1  37824
#define WB_BR1  41920
#define WB_WR2  41984
#define WB_BR2  42176
#define WB_TOT  42240
#define OFF_NBR  (OFF_WB + WB_TOT)           // int32, 320,000 (CSR elist alias pre-knn)
#define OFF_OFFS (OFF_NBR + NPTS*KNNK)       // uint32, NPTS+1
#define WS_TOT_FLOATS (OFF_OFFS + NPTS + 1)
#define WS_NEED_BYTES ((size_t)WS_TOT_FLOATS * 4)

__global__ __launch_bounds__(256) void k_out_zero(float* out, int nelem) {
    int i = blockIdx.x * 256 + threadIdx.x;
    if (i < nelem) out[i] = 0.0f;
}

__global__ __launch_bounds__(256) void k_zero(float* p, int nfloat4) {
    int i = blockIdx.x * 256 + threadIdx.x;
    if (i < nfloat4) { float4 z = {0.f,0.f,0.f,0.f}; ((float4*)p)[i] = z; }
}

__global__ __launch_bounds__(256) void k_prep(
    const float* W1a, const float* b1a,
    const float* W1b, const float* b1b,
    const float* W2a, const float* b2a,
    const float* W2b, const float* b2b,
    const float* We,  const float* be,
    const float* Wp,  const float* bp,
    const float* Wr1, const float* br1,
    const float* Wr2, const float* br2,
    float* wb)
{
    int t = blockIdx.x * blockDim.x + threadIdx.x;
    int gs = gridDim.x * blockDim.x;
    for (int i = t; i < 384;  i += gs) wb[WB_W1A+i] = W1a[i];
    for (int i = t; i < 64;   i += gs) wb[WB_B1A+i] = b1a[i];
    for (int i = t; i < 4096; i += gs) { int j=i>>6, k=i&63; wb[WB_W1BT+i] = W1b[k*64+j]; }
    for (int i = t; i < 64;   i += gs) wb[WB_B1B+i] = b1b[i];
    for (int i = t; i < 8192; i += gs) wb[WB_W2A+i] = W2a[i];
    for (int i = t; i < 64;   i += gs) wb[WB_B2A+i] = b2a[i];
    for (int i = t; i < 4096; i += gs) wb[WB_W2B+i] = W2b[i];
    for (int i = t; i < 64;   i += gs) wb[WB_B2B+i] = b2b[i];
    for (int i = t; i < 16384;i += gs) wb[WB_WE+i]  = We[i];
    for (int i = t; i < 256;  i += gs) wb[WB_BE+i]  = be[i];
    for (int i = t; i < 4096; i += gs) wb[WB_WP+i]  = Wp[i];
    for (int i = t; i < 64;   i += gs) wb[WB_BP+i]  = bp[i];
    for (int i = t; i < 4096; i += gs) wb[WB_WR1+i] = Wr1[i];
    for (int i = t; i < 64;   i += gs) wb[WB_BR1+i] = br1[i];
    for (int i = t; i < 192;  i += gs) wb[WB_WR2+i] = Wr2[i];
    for (int i = t; i < 3;    i += gs) wb[WB_BR2+i] = br2[i];
}

// ---- CSR build: histogram -> scan -> scatter (all aliased into dead ws regions) ----
__global__ __launch_bounds__(256) void k_hist(const int* __restrict__ ei,
                                              unsigned int* __restrict__ counts) {
    int e = blockIdx.x * 256 + threadIdx.x;
    if (e >= NE) return;
    int d = ei[NE + e];
    d = d < 0 ? 0 : (d >= NPTS ? NPTS-1 : d);
    atomicAdd(&counts[d], 1u);
}

// Single block, 64 threads: spans of 313. Writes offs[0..NPTS] and cursor[i]=offs[i].
// cursor may alias counts (read counts[i] before overwrite).
__global__ __launch_bounds__(64) void k_scan(const unsigned int* __restrict__ counts,
                                             unsigned int* __restrict__ cursor,
                                             unsigned int* __restrict__ offs) {
    __shared__ unsigned int ssum[64];
    __shared__ unsigned int sbase[65];
    int t = threadIdx.x;
    int lo = t * 313;
    int hi = lo + 313; if (hi > NPTS) hi = NPTS;
    unsigned int sum = 0;
    for (int i = lo; i < hi; ++i) sum += counts[i];
    ssum[t] = sum;
    __syncthreads();
    if (t == 0) {
        unsigned int run = 0;
        for (int i = 0; i < 64; ++i) { sbase[i] = run; run += ssum[i]; }
        sbase[64] = run;
    }
    __syncthreads();
    unsigned int run = sbase[t];
    for (int i = lo; i < hi; ++i) {
        unsigned int c = counts[i];
        offs[i] = run;
        cursor[i] = run;   // overwrites counts[i] (already read)
        run += c;
    }
    if (t == 0) offs[NPTS] = sbase[64];
}

__global__ __launch_bounds__(256) void k_scatter(const int* __restrict__ ei,
                                                 unsigned int* __restrict__ cursor,
                                                 int* __restrict__ elist) {
    int e = blockIdx.x * 256 + threadIdx.x;
    if (e >= NE) return;
    int d = ei[NE + e];
    d = d < 0 ? 0 : (d >= NPTS ? NPTS-1 : d);
    unsigned int pos = atomicAdd(&cursor[d], 1u);
    elist[pos] = e;
}

// Stage 1 gather: one 64-thread block per point. Per incident edge: 6->64 layer
// (thread t owns channel t), h1 via LDS (double-buffered, 1 barrier/edge),
// 64->64 layer, running max in register. x1 written once, densely. No atomics.
__global__ __launch_bounds__(64) void k_gather(
    const float* __restrict__ dep, const int* __restrict__ ei,
    const int* __restrict__ elist, const unsigned int* __restrict__ offs,
    const float* __restrict__ W1a, const float* __restrict__ b1a,
    const float* __restrict__ W1b, const float* __restrict__ b1b,
    float* __restrict__ x1)
{
    __shared__ float hbuf[2][64];
    int d = blockIdx.x;
    int t = threadIdx.x;
    unsigned int o0 = offs[d], o1 = offs[d+1];
    float xi0 = dep[d*3+0], xi1 = dep[d*3+1], xi2 = dep[d*3+2];
    float wa0 = W1a[t], wa1 = W1a[64+t], wa2 = W1a[128+t];
    float wa3 = W1a[192+t], wa4 = W1a[256+t], wa5 = W1a[320+t];
    float ba = b1a[t], bb = b1b[t];
    float m = 0.0f;          // max of relu(z) over edges; empty segment -> 0 (matches ref)
    int buf = 0;
    for (unsigned int o = o0; o < o1; ++o) {
        int eid = elist[o];
        int s = ei[eid];
        s = s < 0 ? 0 : (s >= NPTS ? NPTS-1 : s);
        float dx0 = dep[s*3+0] - xi0;
        float dx1 = dep[s*3+1] - xi1;
        float dx2 = dep[s*3+2] - xi2;
        float h = ba;
        h = fmaf(xi0, wa0, h); h = fmaf(xi1, wa1, h); h = fmaf(xi2, wa2, h);
        h = fmaf(dx0, wa3, h); h = fmaf(dx1, wa4, h); h = fmaf(dx2, wa5, h);
        h = fmaxf(h, 0.0f);
        hbuf[buf][t] = h;
        __syncthreads();
        const float* hb = hbuf[buf];
        float z = bb;
#pragma unroll 8
        for (int j = 0; j < 64; ++j) z = fmaf(hb[j], W1b[j*64 + t], z);
        m = fmaxf(m, z);     // m >= 0 always, so this equals max(m, relu(z))
        buf ^= 1;            // double buffer: 1 barrier/edge is race-free
    }
    x1[d*64 + t] = m;
}

// Convert x1 rows fp32 -> [hi bf16 x64 | lo bf16 x64] IN PLACE, and write sq (from fp32).
__global__ __launch_bounds__(256) void k_conv(float* __restrict__ x1, float* __restrict__ sq) {
    int n = blockIdx.x * 256 + threadIdx.x;
    if (n >= NPTS) return;
    float* base = x1 + n*64;
    float4 r[16];
#pragma unroll
    for (int i = 0; i < 16; ++i) r[i] = ((const float4*)base)[i];
    float s = 0.f;
#pragma unroll
    for (int i = 0; i < 16; ++i) s += r[i].x*r[i].x + r[i].y*r[i].y + r[i].z*r[i].z + r[i].w*r[i].w;
    sq[n] = s;
    unsigned int* hi = (unsigned int*)base;          // bytes [0,128)
    unsigned int* lo = (unsigned int*)(base + 32);   // bytes [128,256)
#pragma unroll
    for (int j = 0; j < 8; ++j) {
        float v[8] = { r[2*j].x, r[2*j].y, r[2*j].z, r[2*j].w,
                       r[2*j+1].x, r[2*j+1].y, r[2*j+1].z, r[2*j+1].w };
        unsigned int hb[8], lb[8];
#pragma unroll
        for (int e = 0; e < 8; ++e) {
            unsigned int u = __float_as_uint(v[e]);
            hb[e] = (u + 0x7fffu + ((u >> 16) & 1u)) >> 16;           // RNE bf16
            float hf = __uint_as_float(hb[e] << 16);
            float lf = v[e] - hf;
            unsigned int ul = __float_as_uint(lf);
            lb[e] = (ul + 0x7fffu + ((ul >> 16) & 1u)) >> 16;
        }
        uint4 hp, lp;
        hp.x = hb[0] | (hb[1] << 16); hp.y = hb[2] | (hb[3] << 16);
        hp.z = hb[4] | (hb[5] << 16); hp.w = hb[6] | (hb[7] << 16);
        lp.x = lb[0] | (lb[1] << 16); lp.y = lb[2] | (lb[3] << 16);
        lp.z = lb[4] | (lb[5] << 16); lp.w = lb[6] | (lb[7] << 16);
        ((uint4*)hi)[j] = hp;
        ((uint4*)lo)[j] = lp;
    }
}

// KNN v6 (MFMA split-bf16): 64q x 128c tiles, 313 blocks, 512 threads.
// Transposed dT[c][q] pitch 68 (b128 acc stores, ~2-way selection reads),
// named-scalar chunk-skip selection (no spill), register prefetch of next c-tile.
#define RP  136   // staging row pitch in shorts (272 B)
#define DTQ 68    // dT pitch in words ([c][q], q=64)
#define QB  64
__global__ __launch_bounds__(512) void k_knn(
    const float* __restrict__ x1, const float* __restrict__ sqv,
    int* __restrict__ nbr)
{
    __shared__ __align__(16) unsigned short qbuf[QB*RP];        // 17408 B
    __shared__ __align__(16) unsigned char  cbuf_raw[128*RP*2]; // 34816 B (c-tiles / dT / dump alias)
    __shared__ float ssq[128];
    unsigned short* cbuf = (unsigned short*)cbuf_raw;           // [128][RP]
    float* dT = (float*)cbuf_raw;                               // [128 c][DTQ q]
    const int t  = threadIdx.x;
    const int n0 = blockIdx.x * QB;

    // stage q tile: 64 rows x 256 B (hi|lo)
#pragma unroll
    for (int i = 0; i < 2; ++i) {
        int ch = i*512 + t;
        int row = ch >> 4, off = ch & 15;
        uint4 v = make_uint4(0,0,0,0);
        if (n0 + row < NPTS) v = ((const uint4*)(x1 + (n0+row)*64))[off];
        *(uint4*)&qbuf[row*RP + off*8] = v;
    }
    __syncthreads();

    const int lane15 = t & 15;
    const int quad   = (t >> 4) & 3;
    const int w  = t >> 6;
    const int qs = w >> 1, cs = w & 1;
    bf16x8 Ah[2], Al[2];
    {
        const unsigned short* qr = &qbuf[(qs*16 + lane15)*RP + quad*8];
        Ah[0] = *(const bf16x8*)(qr);
        Ah[1] = *(const bf16x8*)(qr + 32);
        Al[0] = *(const bf16x8*)(qr + 64);
        Al[1] = *(const bf16x8*)(qr + 96);
    }
    const int selq = t & 63, sub = (t >> 6) & 3;
    const bool selact = (t < 256);
    float bd[16]; int bi[16];
#pragma unroll
    for (int m = 0; m < 16; ++m) { bd[m] = 1e30f; bi[m] = -1; }
    float wv = 1e30f; int wi = 0;

    // prefetch tile 0 (prow = absolute row for the upcoming tile)
    uint4 pv[4];
    int prow[4], poff[4];
#pragma unroll
    for (int i = 0; i < 4; ++i) {
        int ch = i*512 + t;
        prow[i] = ch >> 4; poff[i] = ch & 15;
        pv[i] = make_uint4(0,0,0,0);
        if (prow[i] < NPTS) pv[i] = ((const uint4*)(x1 + prow[i]*64))[poff[i]];
    }
    float sreg = (t < 128 && t < NPTS) ? sqv[t] : 1e30f;

    const int ntile = (NPTS + 127) / 128;
    for (int tile = 0; tile < ntile; ++tile) {
        const int c0 = tile * 128;
        __syncthreads();   // prev selection done reading dT; cbuf free
#pragma unroll
        for (int i = 0; i < 4; ++i)
            *(uint4*)&cbuf[(prow[i] - c0)*RP + poff[i]*8] = pv[i];
        if (t < 128) ssq[t] = sreg;
        __syncthreads();

        f32x4 acc[4];
#pragma unroll
        for (int t4 = 0; t4 < 4; ++t4) acc[t4] = (f32x4){0.f,0.f,0.f,0.f};
#pragma unroll
        for (int t4 = 0; t4 < 4; ++t4) {
            const unsigned short* cr = &cbuf[(cs*64 + t4*16 + lane15)*RP + quad*8];
            bf16x8 Bh0 = *(const bf16x8*)(cr);
            bf16x8 Bh1 = *(const bf16x8*)(cr + 32);
            bf16x8 Bl0 = *(const bf16x8*)(cr + 64);
            bf16x8 Bl1 = *(const bf16x8*)(cr + 96);
            acc[t4] = __builtin_amdgcn_mfma_f32_16x16x32_bf16(Ah[0], Bh0, acc[t4], 0, 0, 0);
            acc[t4] = __builtin_amdgcn_mfma_f32_16x16x32_bf16(Al[0], Bh0, acc[t4], 0, 0, 0);
            acc[t4] = __builtin_amdgcn_mfma_f32_16x16x32_bf16(Ah[0], Bl0, acc[t4], 0, 0, 0);
            acc[t4] = __builtin_amdgcn_mfma_f32_16x16x32_bf16(Ah[1], Bh1, acc[t4], 0, 0, 0);
            acc[t4] = __builtin_amdgcn_mfma_f32_16x16x32_bf16(Al[1], Bh1, acc[t4], 0, 0, 0);
            acc[t4] = __builtin_amdgcn_mfma_f32_16x16x32_bf16(Ah[1], Bl1, acc[t4], 0, 0, 0);
        }
        __syncthreads();   // all cbuf reads done; dT may overwrite
        // dT[c][q]: lane's 4 acc entries = 4 consecutive q rows -> one b128 per t4
#pragma unroll
        for (int t4 = 0; t4 < 4; ++t4) {
            int c = cs*64 + t4*16 + lane15;
            float4 o; o.x = acc[t4][0]; o.y = acc[t4][1]; o.z = acc[t4][2]; o.w = acc[t4][3];
            *(float4*)&dT[c*DTQ + qs*16 + quad*4] = o;
        }
        __syncthreads();

        // prefetch next tile (latency overlaps selection)
        const int c0n = c0 + 128;
        if (c0n < NPTS) {
#pragma unroll
            for (int i = 0; i < 4; ++i) {
                int row = prow[i] + 128;
                pv[i] = make_uint4(0,0,0,0);
                if (row < NPTS) pv[i] = ((const uint4*)(x1 + row*64))[poff[i]];
                prow[i] = row;
            }
            sreg = (t < 128 && c0n + t < NPTS) ? sqv[c0n + t] : 1e30f;
        }

        if (selact) {
            const float* dcol = dT + selq;
#pragma unroll
            for (int h = 0; h < 4; ++h) {
                int cb8 = sub*32 + h*8;
                float e0 = fmaf(-2.0f, dcol[(cb8+0)*DTQ], ssq[cb8+0]);
                float e1 = fmaf(-2.0f, dcol[(cb8+1)*DTQ], ssq[cb8+1]);
                float e2 = fmaf(-2.0f, dcol[(cb8+2)*DTQ], ssq[cb8+2]);
                float e3 = fmaf(-2.0f, dcol[(cb8+3)*DTQ], ssq[cb8+3]);
                float e4 = fmaf(-2.0f, dcol[(cb8+4)*DTQ], ssq[cb8+4]);
                float e5 = fmaf(-2.0f, dcol[(cb8+5)*DTQ], ssq[cb8+5]);
                float e6 = fmaf(-2.0f, dcol[(cb8+6)*DTQ], ssq[cb8+6]);
                float e7 = fmaf(-2.0f, dcol[(cb8+7)*DTQ], ssq[cb8+7]);
                float mn = fminf(fminf(fminf(e0,e1),fminf(e2,e3)),
                                 fminf(fminf(e4,e5),fminf(e6,e7)));
                if (mn < wv) {
                    float ee[8] = {e0,e1,e2,e3,e4,e5,e6,e7};
#pragma unroll
                    for (int ii = 0; ii < 8; ++ii) {
                        float d2 = ee[ii];
                        int cg = c0 + cb8 + ii;
                        if (d2 < wv && cg < NPTS) {
#pragma unroll
                            for (int m = 0; m < 16; ++m) if (m == wi) { bd[m] = d2; bi[m] = cg; }
                            wv = bd[0]; wi = 0;
#pragma unroll
                            for (int m = 1; m < 16; ++m) if (bd[m] > wv) { wv = bd[m]; wi = m; }
                        }
                    }
                }
            }
        }
    }
    __syncthreads();   // staging regions dead; reuse as dump
    float* fd = (float*)qbuf;        // [64][65] = 16640 B <= 17408
    int*   fi = (int*)cbuf_raw;      // [64][65] = 16640 B <= 34816
    if (selact) {
#pragma unroll
        for (int m = 0; m < 16; ++m) {
            fd[selq*65 + sub*16 + m] = bd[m];
            fi[selq*65 + sub*16 + m] = bi[m];
        }
    }
    __syncthreads();
    if (t < QB && n0 + t < NPTS) {
        const float* dls = fd + t*65;
        const int*   ils = fi + t*65;
        float lastd = -1e38f; int lasti = -1;
        for (int r = 0; r < 16; ++r) {
            float best = 1e30f; int bidx = 0;
            for (int m = 0; m < 64; ++m) {
                float dv2 = dls[m]; int iv = ils[m];
                bool gt = (dv2 > lastd) || (dv2 == lastd && iv > lasti);
                bool lt = (dv2 < best)  || (dv2 == best  && iv < bidx);
                if (gt && lt) { best = dv2; bidx = iv; }
            }
            int bc = bidx < 0 ? 0 : (bidx >= NPTS ? NPTS-1 : bidx);
            nbr[(n0 + t)*16 + r] = bc;
            lastd = best; lasti = bidx;
        }
    }
}

__device__ inline float bf2f(unsigned short u) {
    return __uint_as_float(((unsigned int)u) << 16);
}

// Fused stage-2 MLP (128->64->64, relu, max over 16 nbrs) + head. x1 rows are hi|lo bf16.
__global__ __launch_bounds__(64) void k_fuse(
    const float* __restrict__ x1, const int* __restrict__ nbr,
    const float* __restrict__ wb, float* __restrict__ out)
{
    __shared__ __align__(16) float sxr[64];
    __shared__ __align__(16) float svec[64];
    __shared__ __align__(16) float sx2[64];
    __shared__ int snb[16];
    int n = blockIdx.x;
    int t = threadIdx.x;
    {
        const unsigned short* xr = (const unsigned short*)(x1 + n*64);
        sxr[t] = bf2f(xr[t]) + bf2f(xr[64+t]);
    }
    if (t < 16) snb[t] = nbr[n*16 + t];
    __syncthreads();
    const float* W2a = wb + WB_W2A;   // (128,64)
    const float* W2b = wb + WB_W2B;   // (64,64)
    const float4* sx4 = (const float4*)sxr;
    const float4* sv4 = (const float4*)svec;
    float A = wb[WB_B2A + t];
#pragma unroll
    for (int i4 = 0; i4 < 16; ++i4) {
        float4 v = sx4[i4];
        const float* wr = W2a + i4*256 + t;
        A = fmaf(v.x, wr[0], A); A = fmaf(v.y, wr[64], A);
        A = fmaf(v.z, wr[128], A); A = fmaf(v.w, wr[192], A);
    }
    float x2v = 0.0f;                 // z_k >= 0 (post-relu) -> 0-init == max
    for (int k = 0; k < 16; ++k) {
        int nb = snb[k];
        {
            const unsigned short* yr = (const unsigned short*)(x1 + nb*64);
            svec[t] = bf2f(yr[t]) + bf2f(yr[64+t]);
        }
        __syncthreads();
        float h = A;
#pragma unroll
        for (int i4 = 0; i4 < 16; ++i4) {
            float4 v = sv4[i4];
            float4 u = sx4[i4];
            const float* wr = W2a + (64 + i4*4)*64 + t;
            h = fmaf(v.x-u.x, wr[0], h); h = fmaf(v.y-u.y, wr[64], h);
            h = fmaf(v.z-u.z, wr[128], h); h = fmaf(v.w-u.w, wr[192], h);
        }
        h = fmaxf(h, 0.f);
        __syncthreads();
        svec[t] = h;
        __syncthreads();
        float z = wb[WB_B2B + t];
#pragma unroll
        for (int i4 = 0; i4 < 16; ++i4) {
            float4 v = sv4[i4];
            const float* wr = W2b + i4*256 + t;
            z = fmaf(v.x, wr[0], z); z = fmaf(v.y, wr[64], z);
            z = fmaf(v.z, wr[128], z); z = fmaf(v.w, wr[192], z);
        }
        x2v = fmaxf(x2v, fmaxf(z, 0.f));
        __syncthreads();
    }
    sx2[t] = x2v;
    __syncthreads();
    const float4* sx24 = (const float4*)sx2;
    const float* We  = wb + WB_WE;
    const float* Wp  = wb + WB_WP;
    const float* Wr1 = wb + WB_WR1;
    const float* Wr2 = wb + WB_WR2;
    for (int r = 0; r < 4; ++r) {
        float xe = wb[WB_BE + r*64 + t];
#pragma unroll
        for (int i4 = 0; i4 < 16; ++i4) {
            float4 v = sx24[i4];
            const float* wr = We + i4*1024 + r*64 + t;
            xe = fmaf(v.x, wr[0], xe); xe = fmaf(v.y, wr[256], xe);
            xe = fmaf(v.z, wr[512], xe); xe = fmaf(v.w, wr[768], xe);
        }
        svec[t] = xe;
        __syncthreads();
        float ft = wb[WB_BP + t];
#pragma unroll
        for (int i4 = 0; i4 < 16; ++i4) {
            float4 v = sv4[i4];
            const float* wr = Wp + i4*256 + t;
            ft = fmaf(v.x, wr[0], ft); ft = fmaf(v.y, wr[64], ft);
            ft = fmaf(v.z, wr[128], ft); ft = fmaf(v.w, wr[192], ft);
        }
        __syncthreads();
        svec[t] = ft;
        __syncthreads();
        float hh = wb[WB_BR1 + t];
#pragma unroll
        for (int i4 = 0; i4 < 16; ++i4) {
            float4 v = sv4[i4];
            const float* wr = Wr1 + i4*256 + t;
            hh = fmaf(v.x, wr[0], hh); hh = fmaf(v.y, wr[64], hh);
            hh = fmaf(v.z, wr[128], hh); hh = fmaf(v.w, wr[192], hh);
        }
        hh = fmaxf(hh, 0.f);
        __syncthreads();
        svec[t] = hh;
        __syncthreads();
        if (t < 3) {
            float o = wb[WB_BR2 + t];
            for (int i = 0; i < 64; ++i) o = fmaf(svec[i], Wr2[i*3 + t], o);
            int m = r * NPTS + n;
            out[m*3 + t] = o;
        }
        __syncthreads();
    }
}

extern "C" void kernel_launch(void* const* d_in, const int* in_sizes, int n_in,
                              void* d_out, int out_size, void* d_ws, size_t ws_size,
                              hipStream_t stream)
{
    const float* dep = (const float*)d_in[0];
    const float* W1a = (const float*)d_in[1];
    const float* b1a = (const float*)d_in[2];
    const float* W1b = (const float*)d_in[3];
    const float* b1b = (const float*)d_in[4];
    const float* W2a = (const float*)d_in[5];
    const float* b2a = (const float*)d_in[6];
    const float* W2b = (const float*)d_in[7];
    const float* b2b = (const float*)d_in[8];
    const float* We  = (const float*)d_in[9];
    const float* be  = (const float*)d_in[10];
    const float* Wp  = (const float*)d_in[11];
    const float* bp  = (const float*)d_in[12];
    const float* Wr1 = (const float*)d_in[13];
    const float* br1 = (const float*)d_in[14];
    const float* Wr2 = (const float*)d_in[15];
    const float* br2 = (const float*)d_in[16];
    const int* ei = (const int*)d_in[17];

    if (ws_size < WS_NEED_BYTES || d_ws == nullptr) {
        k_out_zero<<<(out_size + 255)/256, 256, 0, stream>>>((float*)d_out, out_size);
        return;
    }

    float* ws   = (float*)d_ws;
    float* x1   = ws + OFF_X1;
    float* sq   = ws + OFF_SQ;
    float* wbuf = ws + OFF_WB;
    int*   nbr  = (int*)(ws + OFF_NBR);
    unsigned int* counts = (unsigned int*)(ws + OFF_SQ);   // alias (pre-conv)
    int*   elist = (int*)(ws + OFF_NBR);                   // alias (pre-knn)
    unsigned int* offs = (unsigned int*)(ws + OFF_OFFS);

    k_zero<<<(NPTS/4 + 255)/256, 256, 0, stream>>>((float*)counts, NPTS/4);
    k_prep<<<64, 256, 0, stream>>>(W1a,b1a,W1b,b1b,W2a,b2a,W2b,b2b,We,be,Wp,bp,Wr1,br1,Wr2,br2, wbuf);
    k_hist<<<NE/256, 256, 0, stream>>>(ei, counts);
    k_scan<<<1, 64, 0, stream>>>(counts, counts, offs);
    k_scatter<<<NE/256, 256, 0, stream>>>(ei, counts, elist);
    k_gather<<<NPTS, 64, 0, stream>>>(dep, ei, elist, offs, W1a, b1a, W1b, b1b, x1);
    k_conv<<<(NPTS+255)/256, 256, 0, stream>>>(x1, sq);
    k_knn<<<(NPTS+QB-1)/QB, 512, 0, stream>>>(x1, sq, nbr);
    k_fuse<<<NPTS, 64, 0, stream>>>(x1, nbr, wbuf, (float*)d_out);
}